// Round 15
// baseline (181.965 us; speedup 1.0000x reference)
//
#include <hip/hip_runtime.h>

#define NN 50000
#define NE 800000
#define CAP 64         // per-dst bucket capacity; Poisson(16) P(>64) ~ 1e-18
#define KC 72          // 576/8 k-chunks
#define RNG 6250       // NN/8, dst range per XCD slice
#define EPB 2047       // edges scanned per scatter block (391*2047 >= NE)

typedef __bf16 bf16x8 __attribute__((ext_vector_type(8)));
typedef float f32x4 __attribute__((ext_vector_type(4)));
typedef float f32x2 __attribute__((ext_vector_type(2)));
typedef unsigned short ushort;
typedef unsigned int uint;

__device__ inline ushort f2bf(float x) {  // RNE float->bf16
  uint u = __builtin_bit_cast(uint, x);
  u += 0x7FFF + ((u >> 16) & 1);
  return (ushort)(u >> 16);
}
__device__ inline float bf2f(ushort u) {
  return __builtin_bit_cast(float, (uint)u << 16);
}

// ---------------- merged build: XCD-partitioned scatter + fbf + packs --------
// (unchanged from R13 — proven: build dropped out of top-5)

__device__ inline void wprep_body(const float* __restrict__ basis,
                                  const float* __restrict__ loopw,
                                  ushort* __restrict__ W2, int DOUT, int NCOLS,
                                  int idx) {
  int total = KC * NCOLS * 8;
  if (idx >= total) return;
  int j = idx & 7;
  int n = (idx >> 3) % NCOLS;
  int kc = idx / (8 * NCOLS);
  int k = kc * 8 + j;
  float v = 0.f;
  if (n < DOUT) v = (k < 512) ? basis[k * DOUT + n] : loopw[(k - 512) * DOUT + n];
  W2[((size_t)kc * NCOLS + n) * 8 + j] = f2bf(v);
}

__global__ __launch_bounds__(256) void build_kernel(
    const int* __restrict__ dstv, const int* __restrict__ srcv,
    const int* __restrict__ etv, int* __restrict__ cursor, int* __restrict__ pk,
    const float* __restrict__ f, ushort* __restrict__ fb,
    const float* __restrict__ b0, const float* __restrict__ l0, ushort* __restrict__ W0,
    const float* __restrict__ b1, const float* __restrict__ l1, ushort* __restrict__ W1,
    const float* __restrict__ b2, const float* __restrict__ l2, ushort* __restrict__ W2,
    const float* __restrict__ c0, const float* __restrict__ c1,
    const float* __restrict__ c2, float* __restrict__ cp) {
  int blk = blockIdx.x;
  int tid = threadIdx.x;
  if (blk < 3128) {
    int sel = blk & 7;
    int sub = blk >> 3;          // 0..390
    int lo = sel * RNG;
    int start = sub * EPB;
    for (int t = tid; t < EPB; t += 256) {
      int i = start + t;
      if (i >= NE) break;
      int d = dstv[i];
      if ((uint)(d - lo) < (uint)RNG) {
        int p = atomicAdd(&cursor[d], 1);
        if (p < CAP) pk[d * CAP + p] = (etv[i] << 16) | srcv[i];
      }
    }
  } else if (blk < 6253) {
    int i = (blk - 3128) * 256 + tid;  // NN*16 = 800000 ushort4 granules
    if (i < NN * 16) {
      float4 v = ((const float4*)f)[i];
      ushort4 u;
      u.x = f2bf(v.x); u.y = f2bf(v.y); u.z = f2bf(v.z); u.w = f2bf(v.w);
      ((ushort4*)fb)[i] = u;
    }
  } else if (blk < 6397) {
    wprep_body(b0, l0, W0, 64, 64, (blk - 6253) * 256 + tid);
  } else if (blk < 6541) {
    wprep_body(b1, l1, W1, 64, 64, (blk - 6397) * 256 + tid);
  } else if (blk < 6577) {
    wprep_body(b2, l2, W2, 8, 16, (blk - 6541) * 256 + tid);
  } else {
    // cpad[3][17][8]: per-layer comp + zero sentinel row 16
    int idx = (blk - 6577) * 256 + tid;  // 0..511
    if (idx < 408) {
      int l = idx / 136, k = idx % 136;
      const float* src = (l == 0) ? c0 : ((l == 1) ? c1 : c2);
      cp[idx] = (k < 128) ? src[k] : 0.f;
    }
  }
}

// ---------------- fused layer: software-pipelined agg + MFMA dense ----------
// 16 waves, 1 dst each. Phase A in 8-edge rounds, cross-round double-buffered:
// round r+1's 8 per-lane gathers are ISSUED (into hv1[]) before round r's
// values (hv0[]) are consumed; explicit rotation hv0<-hv1 forces the loads to
// stay in flight across the consume (the compiler cannot sink them to their
// use — the use is an iteration away). Masked tail -> comp row 16 (zeros),
// src 0 (finite, L1-hot). LDS X [kc][m^(kc&7)][8] bf16 XOR swizzle.
// Phase B: swapped-operand mfma_16x16x32_bf16 (waves 0..3 / wave 0).

#define DECODE_ISSUE(r, rs, hv)                                              \
  {                                                                          \
    int4 e0 = p4[2 * (r)];                                                   \
    int4 e1 = p4[2 * (r) + 1];                                               \
    int pe[8] = {e0.x, e0.y, e0.z, e0.w, e1.x, e1.y, e1.z, e1.w};            \
    _Pragma("unroll")                                                        \
    for (int i = 0; i < 8; ++i) {                                            \
      uint up = (uint)__builtin_amdgcn_readfirstlane(pe[i]);                 \
      int valid = 8 * (r) + i < dw;                                          \
      rs[i] = valid ? (up >> 16) : 16u;                                      \
      uint ss = valid ? (up & 0xFFFFu) : 0u;                                 \
      hv[i] = bf2f(hb[(size_t)ss * 64 + lane]);                              \
    }                                                                        \
  }

template <int DOUT, int NCOLS, bool OBF>
__global__ __launch_bounds__(1024, 8) void layer_kernel(
    const ushort* __restrict__ hb,     // [NN,64] bf16
    const float* __restrict__ cpad,    // [17,8] f32 (row 16 = zeros)
    const int* __restrict__ degv,
    const int* __restrict__ pk,        // [NN,CAP]
    const ushort* __restrict__ W2,     // [KC][NCOLS][8] bf16
    const float* __restrict__ bias,    // [DOUT]
    void* __restrict__ outp,           // [NN,DOUT] bf16 (OBF) or f32
    float slope)
{
  __shared__ ushort X[KC][16][8];      // 18432 B
  int tid = threadIdx.x;
  int wave = tid >> 6;
  int lane = tid & 63;
  int dbase = blockIdx.x * 16;         // grid 3125 * 16 = NN exactly
  int d = __builtin_amdgcn_readfirstlane(dbase + wave);

  // ---- Phase A ----
  int deg = degv[d];
  int dw = __builtin_amdgcn_readfirstlane(deg > CAP ? CAP : deg);
  const int4* p4 = (const int4*)(pk + (size_t)d * CAP);
  int ng = (dw + 7) >> 3;              // 8-edge rounds

  f32x2 acc2[4] = {{0.f, 0.f}, {0.f, 0.f}, {0.f, 0.f}, {0.f, 0.f}};
  uint rs0[8], rs1[8];
  float hv0[8], hv1[8];
  if (ng > 0) DECODE_ISSUE(0, rs0, hv0);
  for (int r = 0; r < ng; ++r) {
    if (r + 1 < ng) DECODE_ISSUE(r + 1, rs1, hv1);   // next round in flight
#pragma unroll
    for (int i = 0; i < 8; ++i) {                    // consume current round
      const f32x2* c2 = (const f32x2*)(cpad + rs0[i] * 8);
      f32x2 h2 = {hv0[i], hv0[i]};
#pragma unroll
      for (int j = 0; j < 4; ++j)
        acc2[j] = __builtin_elementwise_fma(c2[j], h2, acc2[j]);
    }
#pragma unroll
    for (int i = 0; i < 8; ++i) { rs0[i] = rs1[i]; hv0[i] = hv1[i]; }
  }

  float inv = 1.0f / (float)(deg > 1 ? deg : 1);
  int jj = lane & 7;
  int csub = lane >> 3;
#pragma unroll
  for (int b = 0; b < 8; ++b) {
    float v = ((b & 1) ? acc2[b >> 1].y : acc2[b >> 1].x) * inv;
    X[b * 8 + csub][wave ^ csub][jj] = f2bf(v);   // row XOR swizzle (kc&7==csub)
  }
  X[64 + csub][wave ^ csub][jj] = hb[(size_t)d * 64 + lane];  // self-loop input
  __syncthreads();

  // ---- Phase B ----
  if (wave < (DOUT == 64 ? 4 : 1)) {
    int q = lane >> 4;
    int r = lane & 15;
    f32x4 accd = {0.f, 0.f, 0.f, 0.f};
#pragma unroll
    for (int ks = 0; ks < 18; ++ks) {
      int kc = ks * 4 + q;
      bf16x8 bfrag = *(const bf16x8*)&X[kc][r ^ (kc & 7)][0];
      bf16x8 afrag = *(const bf16x8*)(W2 + ((size_t)kc * NCOLS + wave * 16 + r) * 8);
      accd = __builtin_amdgcn_mfma_f32_16x16x32_bf16(afrag, bfrag, accd, 0, 0, 0);
    }
    int m = dbase + r;
    int nb = wave * 16 + q * 4;
    if (nb < DOUT) {
      float4 bv = *(const float4*)(bias + nb);
      float v0 = accd[0] + bv.x;
      float v1 = accd[1] + bv.y;
      float v2 = accd[2] + bv.z;
      float v3 = accd[3] + bv.w;
      v0 = v0 > 0.f ? v0 : slope * v0;
      v1 = v1 > 0.f ? v1 : slope * v1;
      v2 = v2 > 0.f ? v2 : slope * v2;
      v3 = v3 > 0.f ? v3 : slope * v3;
      if (OBF) {
        ushort4 u;
        u.x = f2bf(v0); u.y = f2bf(v1); u.z = f2bf(v2); u.w = f2bf(v3);
        *(ushort4*)((ushort*)outp + (size_t)m * DOUT + nb) = u;
      } else {
        *(float4*)((float*)outp + (size_t)m * DOUT + nb) = float4{v0, v1, v2, v3};
      }
    }
  }
}

// ---------------- launch ----------------

extern "C" void kernel_launch(void* const* d_in, const int* in_sizes, int n_in,
                              void* d_out, int out_size, void* d_ws, size_t ws_size,
                              hipStream_t stream) {
  const float* features = (const float*)d_in[0];
  const float* basis0   = (const float*)d_in[2];
  const float* comp0    = (const float*)d_in[3];
  const float* loop0    = (const float*)d_in[4];
  const float* bias0    = (const float*)d_in[5];
  const float* basis1   = (const float*)d_in[6];
  const float* comp1    = (const float*)d_in[7];
  const float* loop1    = (const float*)d_in[8];
  const float* bias1    = (const float*)d_in[9];
  const float* basis2   = (const float*)d_in[10];
  const float* comp2    = (const float*)d_in[11];
  const float* loop2    = (const float*)d_in[12];
  const float* bias2    = (const float*)d_in[13];
  const int* etypes     = (const int*)d_in[14];
  const int* srcv       = (const int*)d_in[15];
  const int* dstv       = (const int*)d_in[16];

  char* ws = (char*)d_ws;
  size_t off = 0;
  auto alloc = [&](size_t bytes) {
    void* p = ws + off;
    off += (bytes + 255) & ~(size_t)255;
    return p;
  };
  int* cnt      = (int*)alloc(NN * sizeof(int));
  int* pk       = (int*)alloc((size_t)NN * CAP * sizeof(int));
  ushort* W2_0  = (ushort*)alloc((size_t)KC * 64 * 8 * sizeof(ushort));
  ushort* W2_1  = (ushort*)alloc((size_t)KC * 64 * 8 * sizeof(ushort));
  ushort* W2_2  = (ushort*)alloc((size_t)KC * 16 * 8 * sizeof(ushort));
  float* cpad   = (float*)alloc(3 * 136 * sizeof(float));
  ushort* fbf   = (ushort*)alloc((size_t)NN * 64 * sizeof(ushort));
  ushort* hA    = (ushort*)alloc((size_t)NN * 64 * sizeof(ushort));
  ushort* hB    = (ushort*)alloc((size_t)NN * 64 * sizeof(ushort));

  hipMemsetAsync(cnt, 0, NN * sizeof(int), stream);
  build_kernel<<<6579, 256, 0, stream>>>(dstv, srcv, etypes, cnt, pk,
                                         features, fbf,
                                         basis0, loop0, W2_0,
                                         basis1, loop1, W2_1,
                                         basis2, loop2, W2_2,
                                         comp0, comp1, comp2, cpad);

  layer_kernel<64, 64, true><<<3125, 1024, 0, stream>>>(
      fbf, cpad + 0 * 136, cnt, pk, W2_0, bias0, hA, 0.01f);
  layer_kernel<64, 64, true><<<3125, 1024, 0, stream>>>(
      hA, cpad + 1 * 136, cnt, pk, W2_1, bias1, hB, 0.01f);
  layer_kernel<8, 16, false><<<3125, 1024, 0, stream>>>(
      hB, cpad + 2 * 136, cnt, pk, W2_2, bias2, d_out, 0.0f);
}

// Round 16
// 158.701 us; speedup vs baseline: 1.1466x; 1.1466x over previous
//
#include <hip/hip_runtime.h>

#define NN 50000
#define NE 800000
#define CAP 64         // per-dst bucket capacity; Poisson(16) P(>64) ~ 1e-18
#define KC 72          // 576/8 k-chunks
#define RNG 6250       // NN/8, dst range per XCD slice
#define EPB 2047       // edges scanned per scatter block (391*2047 >= NE)

typedef __bf16 bf16x8 __attribute__((ext_vector_type(8)));
typedef float f32x4 __attribute__((ext_vector_type(4)));
typedef unsigned short ushort;
typedef unsigned int uint;

__device__ inline ushort f2bf(float x) {  // RNE float->bf16
  uint u = __builtin_bit_cast(uint, x);
  u += 0x7FFF + ((u >> 16) & 1);
  return (ushort)(u >> 16);
}
__device__ inline float bf2f(ushort u) {
  return __builtin_bit_cast(float, (uint)u << 16);
}

// ---------------- merged build: XCD-partitioned scatter + fbf + packs --------
// (unchanged from R13 — proven: build dropped out of top-5)

__device__ inline void wprep_body(const float* __restrict__ basis,
                                  const float* __restrict__ loopw,
                                  ushort* __restrict__ W2, int DOUT, int NCOLS,
                                  int idx) {
  int total = KC * NCOLS * 8;
  if (idx >= total) return;
  int j = idx & 7;
  int n = (idx >> 3) % NCOLS;
  int kc = idx / (8 * NCOLS);
  int k = kc * 8 + j;
  float v = 0.f;
  if (n < DOUT) v = (k < 512) ? basis[k * DOUT + n] : loopw[(k - 512) * DOUT + n];
  W2[((size_t)kc * NCOLS + n) * 8 + j] = f2bf(v);
}

__global__ __launch_bounds__(256) void build_kernel(
    const int* __restrict__ dstv, const int* __restrict__ srcv,
    const int* __restrict__ etv, int* __restrict__ cursor, int* __restrict__ pk,
    const float* __restrict__ f, ushort* __restrict__ fb,
    const float* __restrict__ b0, const float* __restrict__ l0, ushort* __restrict__ W0,
    const float* __restrict__ b1, const float* __restrict__ l1, ushort* __restrict__ W1,
    const float* __restrict__ b2, const float* __restrict__ l2, ushort* __restrict__ W2,
    const float* __restrict__ c0, const float* __restrict__ c1,
    const float* __restrict__ c2, float* __restrict__ cp) {
  int blk = blockIdx.x;
  int tid = threadIdx.x;
  if (blk < 3128) {
    int sel = blk & 7;
    int sub = blk >> 3;          // 0..390
    int lo = sel * RNG;
    int start = sub * EPB;
    for (int t = tid; t < EPB; t += 256) {
      int i = start + t;
      if (i >= NE) break;
      int d = dstv[i];
      if ((uint)(d - lo) < (uint)RNG) {
        int p = atomicAdd(&cursor[d], 1);
        if (p < CAP) pk[d * CAP + p] = (etv[i] << 16) | srcv[i];
      }
    }
  } else if (blk < 6253) {
    int i = (blk - 3128) * 256 + tid;  // NN*16 = 800000 ushort4 granules
    if (i < NN * 16) {
      float4 v = ((const float4*)f)[i];
      ushort4 u;
      u.x = f2bf(v.x); u.y = f2bf(v.y); u.z = f2bf(v.z); u.w = f2bf(v.w);
      ((ushort4*)fb)[i] = u;
    }
  } else if (blk < 6397) {
    wprep_body(b0, l0, W0, 64, 64, (blk - 6253) * 256 + tid);
  } else if (blk < 6541) {
    wprep_body(b1, l1, W1, 64, 64, (blk - 6397) * 256 + tid);
  } else if (blk < 6577) {
    wprep_body(b2, l2, W2, 8, 16, (blk - 6541) * 256 + tid);
  } else {
    // cpad[3][17][8]: per-layer comp + zero sentinel row 16
    int idx = (blk - 6577) * 256 + tid;  // 0..511
    if (idx < 408) {
      int l = idx / 136, k = idx % 136;
      const float* src = (l == 0) ? c0 : ((l == 1) ? c1 : c2);
      cp[idx] = (k < 128) ? src[k] : 0.f;
    }
  }
}

// ---------------- fused layer: high-occupancy agg + MFMA dense --------------
// 256 threads = 4 waves; 16 dsts/block (4 per wave, serial). At LDS 18.4KB and
// __launch_bounds__(256,8): 8 blocks/CU = 32 waves/CU (vs ~17 at the 1024-
// thread geometry) -> ~2x outstanding gathers per CU. Phase A is R8's proven
// walk: 4-edge int4 groups + next-group prefetch + scalar-comp s_loads +
// scalar fmaf. LDS X [kc][m^(kc&7)][8] bf16 XOR swizzle (2-way banks, free).
// Phase B identical W2 traffic (16-dst tile kept): swapped-operand
// mfma_16x16x32_bf16, waves 0..3 (DOUT=64) / wave 0 (DOUT=8).

template <int DOUT, int NCOLS, bool OBF>
__global__ __launch_bounds__(256, 8) void layer_kernel(
    const ushort* __restrict__ hb,     // [NN,64] bf16
    const float* __restrict__ cpad,    // [17,8] f32 (row 16 = zeros)
    const int* __restrict__ degv,
    const int* __restrict__ pk,        // [NN,CAP]
    const ushort* __restrict__ W2,     // [KC][NCOLS][8] bf16
    const float* __restrict__ bias,    // [DOUT]
    void* __restrict__ outp,           // [NN,DOUT] bf16 (OBF) or f32
    float slope)
{
  __shared__ ushort X[KC][16][8];      // 18432 B
  int tid = threadIdx.x;
  int wave = tid >> 6;                 // 0..3
  int lane = tid & 63;
  int jj = lane & 7;
  int csub = lane >> 3;
  int dbase = blockIdx.x * 16;         // grid 3125 * 16 = NN exactly

  // ---- Phase A: 4 dsts per wave, serial ----
  for (int t = 0; t < 4; ++t) {
    int dl = wave * 4 + t;             // X row 0..15
    int d = __builtin_amdgcn_readfirstlane(dbase + dl);
    int deg = degv[d];
    int dw = deg > CAP ? CAP : deg;
    const int* pb = pk + (size_t)d * CAP;
    const int4* p4 = (const int4*)pb;
    int ng = dw >> 2;

    float acc[8] = {0.f, 0.f, 0.f, 0.f, 0.f, 0.f, 0.f, 0.f};
    if (ng > 0) {
      int4 pv = p4[0];
      for (int g = 0; g < ng; ++g) {
        int4 nv = pv;
        if (g + 1 < ng) nv = p4[g + 1];  // prefetch next group
        {
          int pe = __builtin_amdgcn_readfirstlane(pv.x);
          float hv = bf2f(hb[(size_t)(pe & 0xFFFF) * 64 + lane]);
          const float* c = cpad + (pe >> 16) * 8;
#pragma unroll
          for (int b = 0; b < 8; ++b) acc[b] = fmaf(c[b], hv, acc[b]);
        }
        {
          int pe = __builtin_amdgcn_readfirstlane(pv.y);
          float hv = bf2f(hb[(size_t)(pe & 0xFFFF) * 64 + lane]);
          const float* c = cpad + (pe >> 16) * 8;
#pragma unroll
          for (int b = 0; b < 8; ++b) acc[b] = fmaf(c[b], hv, acc[b]);
        }
        {
          int pe = __builtin_amdgcn_readfirstlane(pv.z);
          float hv = bf2f(hb[(size_t)(pe & 0xFFFF) * 64 + lane]);
          const float* c = cpad + (pe >> 16) * 8;
#pragma unroll
          for (int b = 0; b < 8; ++b) acc[b] = fmaf(c[b], hv, acc[b]);
        }
        {
          int pe = __builtin_amdgcn_readfirstlane(pv.w);
          float hv = bf2f(hb[(size_t)(pe & 0xFFFF) * 64 + lane]);
          const float* c = cpad + (pe >> 16) * 8;
#pragma unroll
          for (int b = 0; b < 8; ++b) acc[b] = fmaf(c[b], hv, acc[b]);
        }
        pv = nv;
      }
    }
    for (int j = dw & ~3; j < dw; ++j) {  // tail (<=3, wave-uniform)
      int pe = __builtin_amdgcn_readfirstlane(pb[j]);
      float hv = bf2f(hb[(size_t)(pe & 0xFFFF) * 64 + lane]);
      const float* c = cpad + (pe >> 16) * 8;
#pragma unroll
      for (int b = 0; b < 8; ++b) acc[b] = fmaf(c[b], hv, acc[b]);
    }

    float inv = 1.0f / (float)(deg > 1 ? deg : 1);
#pragma unroll
    for (int b = 0; b < 8; ++b)
      X[b * 8 + csub][dl ^ csub][jj] = f2bf(acc[b] * inv);  // XOR swizzle
    X[64 + csub][dl ^ csub][jj] = hb[(size_t)d * 64 + lane]; // self-loop input
  }
  __syncthreads();

  // ---- Phase B ----
  if (wave < (DOUT == 64 ? 4 : 1)) {
    int q = lane >> 4;
    int r = lane & 15;
    f32x4 accd = {0.f, 0.f, 0.f, 0.f};
#pragma unroll
    for (int ks = 0; ks < 18; ++ks) {
      int kc = ks * 4 + q;
      bf16x8 bfrag = *(const bf16x8*)&X[kc][r ^ (kc & 7)][0];
      bf16x8 afrag = *(const bf16x8*)(W2 + ((size_t)kc * NCOLS + wave * 16 + r) * 8);
      accd = __builtin_amdgcn_mfma_f32_16x16x32_bf16(afrag, bfrag, accd, 0, 0, 0);
    }
    int m = dbase + r;
    int nb = wave * 16 + q * 4;
    if (nb < DOUT) {
      float4 bv = *(const float4*)(bias + nb);
      float v0 = accd[0] + bv.x;
      float v1 = accd[1] + bv.y;
      float v2 = accd[2] + bv.z;
      float v3 = accd[3] + bv.w;
      v0 = v0 > 0.f ? v0 : slope * v0;
      v1 = v1 > 0.f ? v1 : slope * v1;
      v2 = v2 > 0.f ? v2 : slope * v2;
      v3 = v3 > 0.f ? v3 : slope * v3;
      if (OBF) {
        ushort4 u;
        u.x = f2bf(v0); u.y = f2bf(v1); u.z = f2bf(v2); u.w = f2bf(v3);
        *(ushort4*)((ushort*)outp + (size_t)m * DOUT + nb) = u;
      } else {
        *(float4*)((float*)outp + (size_t)m * DOUT + nb) = float4{v0, v1, v2, v3};
      }
    }
  }
}

// ---------------- launch ----------------

extern "C" void kernel_launch(void* const* d_in, const int* in_sizes, int n_in,
                              void* d_out, int out_size, void* d_ws, size_t ws_size,
                              hipStream_t stream) {
  const float* features = (const float*)d_in[0];
  const float* basis0   = (const float*)d_in[2];
  const float* comp0    = (const float*)d_in[3];
  const float* loop0    = (const float*)d_in[4];
  const float* bias0    = (const float*)d_in[5];
  const float* basis1   = (const float*)d_in[6];
  const float* comp1    = (const float*)d_in[7];
  const float* loop1    = (const float*)d_in[8];
  const float* bias1    = (const float*)d_in[9];
  const float* basis2   = (const float*)d_in[10];
  const float* comp2    = (const float*)d_in[11];
  const float* loop2    = (const float*)d_in[12];
  const float* bias2    = (const float*)d_in[13];
  const int* etypes     = (const int*)d_in[14];
  const int* srcv       = (const int*)d_in[15];
  const int* dstv       = (const int*)d_in[16];

  char* ws = (char*)d_ws;
  size_t off = 0;
  auto alloc = [&](size_t bytes) {
    void* p = ws + off;
    off += (bytes + 255) & ~(size_t)255;
    return p;
  };
  int* cnt      = (int*)alloc(NN * sizeof(int));
  int* pk       = (int*)alloc((size_t)NN * CAP * sizeof(int));
  ushort* W2_0  = (ushort*)alloc((size_t)KC * 64 * 8 * sizeof(ushort));
  ushort* W2_1  = (ushort*)alloc((size_t)KC * 64 * 8 * sizeof(ushort));
  ushort* W2_2  = (ushort*)alloc((size_t)KC * 16 * 8 * sizeof(ushort));
  float* cpad   = (float*)alloc(3 * 136 * sizeof(float));
  ushort* fbf   = (ushort*)alloc((size_t)NN * 64 * sizeof(ushort));
  ushort* hA    = (ushort*)alloc((size_t)NN * 64 * sizeof(ushort));
  ushort* hB    = (ushort*)alloc((size_t)NN * 64 * sizeof(ushort));

  hipMemsetAsync(cnt, 0, NN * sizeof(int), stream);
  build_kernel<<<6579, 256, 0, stream>>>(dstv, srcv, etypes, cnt, pk,
                                         features, fbf,
                                         basis0, loop0, W2_0,
                                         basis1, loop1, W2_1,
                                         basis2, loop2, W2_2,
                                         comp0, comp1, comp2, cpad);

  layer_kernel<64, 64, true><<<3125, 256, 0, stream>>>(
      fbf, cpad + 0 * 136, cnt, pk, W2_0, bias0, hA, 0.01f);
  layer_kernel<64, 64, true><<<3125, 256, 0, stream>>>(
      hA, cpad + 1 * 136, cnt, pk, W2_1, bias1, hB, 0.01f);
  layer_kernel<8, 16, false><<<3125, 256, 0, stream>>>(
      hB, cpad + 2 * 136, cnt, pk, W2_2, bias2, d_out, 0.0f);
}